// Round 14
// baseline (93.328 us; speedup 1.0000x reference)
//
#include <hip/hip_runtime.h>
#include <cmath>

#define N_NODES 10000
#define UNITS   64
#define IND     2
#define BATCH   16
#define NEDGE   80000
#define FDIM    66            // IND + UNITS
#define OG      128           // 2*UNITS
#define OC      64            // UNITS
#define HXS     (N_NODES*UNITS)
#define INS     (N_NODES*IND)
#define KTILES  5             // ceil(132/32)
#define FQ      17            // f-quads per row (F padded 66->68)
#define CHUNKS  272           // 16*17 quads per row
#define LDSC    21            // padded fq stride in LDS
#define CAP     64            // bucket capacity per node (mean deg 8)

typedef __attribute__((ext_vector_type(8))) short bf16x8;
typedef __attribute__((ext_vector_type(4))) float f32x4;
typedef __attribute__((ext_vector_type(2))) float f32x2;
typedef unsigned long long u64;

__device__ __forceinline__ float bf2f(unsigned short u) {
  union { unsigned u; float f; } v; v.u = ((unsigned)u) << 16; return v.f;
}
__device__ __forceinline__ unsigned short f2bf(float x) {
  union { float f; unsigned u; } v; v.f = x;
  unsigned r = v.u + 0x7fffu + ((v.u >> 16) & 1u);
  return (unsigned short)(r >> 16);
}
__device__ __forceinline__ unsigned cvt2bf(float a, float b) {   // lo=bf16(a), hi=bf16(b)
  unsigned r; asm("v_cvt_pk_bf16_f32 %0, %1, %2" : "=v"(r) : "v"(a), "v"(b)); return r;
}
__device__ __forceinline__ unsigned pk4fp8(float a, float b, float c, float d) {
  int v = __builtin_amdgcn_cvt_pk_fp8_f32(a, b, 0, false);
  v = __builtin_amdgcn_cvt_pk_fp8_f32(c, d, v, true);
  return (unsigned)v;
}
__device__ __forceinline__ unsigned char f2fp8(float a) {
  return (unsigned char)(__builtin_amdgcn_cvt_pk_fp8_f32(a, 0.f, 0, false) & 0xff);
}

// ================= fused prep: pack W | fill buckets | build X8 + X0bf =================
__global__ __launch_bounds__(256) void prep_kernel(
    const float* __restrict__ inputs, const float* __restrict__ hx,
    const float* __restrict__ w1mu, const float* __restrict__ w1ls, const float* __restrict__ ew1,
    const float* __restrict__ b1mu, const float* __restrict__ b1ls, const float* __restrict__ eb1,
    const float* __restrict__ w2mu, const float* __restrict__ w2ls, const float* __restrict__ ew2,
    const float* __restrict__ b2mu, const float* __restrict__ b2ls, const float* __restrict__ eb2,
    const int* __restrict__ erow, const int* __restrict__ ecol, const float* __restrict__ eval,
    short* __restrict__ W1p, short* __restrict__ W2p,
    float* __restrict__ B1, float* __restrict__ B2,
    int* __restrict__ cnt, u64* __restrict__ epk,
    unsigned* __restrict__ X8, uint2* __restrict__ X0bf) {
  int blk = blockIdx.x, t = threadIdx.x;
  if (blk < 16) {                    // ---- pack W (fused reparam) ----
    int i = blk * 256 + t;
    if (i < 2560) {
      int l = i & 63, kt = (i >> 6) % KTILES, nt = i / (KTILES * 64);
      int o = nt * 16 + (l & 15), s = l >> 4;
      bf16x8 fr;
#pragma unroll
      for (int j = 0; j < 8; ++j) {
        int f = kt * 16 + s * 4 + (j & 3);
        int src = j >> 2;
        float w = 0.f;
        if (f < FDIM) { int idx = (2 * f + src) * OG + o; w = w1mu[idx] + __expf(w1ls[idx]) * ew1[idx]; }
        fr[j] = (short)f2bf(w);
      }
      *((bf16x8*)W1p + i) = fr;
    } else if (i < 3840) {
      int i2 = i - 2560;
      int l = i2 & 63, kt = (i2 >> 6) % KTILES, nt = i2 / (KTILES * 64);
      int o = nt * 16 + (l & 15), s = l >> 4;
      bf16x8 fr;
#pragma unroll
      for (int j = 0; j < 8; ++j) {
        int f = kt * 16 + s * 4 + (j & 3);
        int src = j >> 2;
        float w = 0.f;
        if (f < FDIM) { int idx = (2 * f + src) * OC + o; w = w2mu[idx] + __expf(w2ls[idx]) * ew2[idx]; }
        fr[j] = (short)f2bf(w);
      }
      *((bf16x8*)W2p + i2) = fr;
    } else if (i < 3968) {
      int j = i - 3840; B1[j] = b1mu[j] + __expf(b1ls[j]) * eb1[j];
    } else if (i < 4032) {
      int j = i - 3968; B2[j] = b2mu[j] + __expf(b2ls[j]) * eb2[j];
    }
  } else if (blk < 16 + 313) {       // ---- fill buckets ----
    int i = (blk - 16) * 256 + t;
    if (i < NEDGE) {
      int r = erow[i];
      int pos = atomicAdd(&cnt[r], 1);
      if (pos < CAP)
        epk[(size_t)r * CAP + pos] =
            (u64)(unsigned)(ecol[i] * CHUNKS) | ((u64)__float_as_uint(eval[i]) << 32);
    }
  } else {                           // ---- build X8 (fp8) + X0bf (bf16) ----
    int i = (blk - 329) * 256 + t;
    if (i >= N_NODES * CHUNKS) return;
    int n = i / CHUNKS;
    int c = i - n * CHUNKS;
    int b = c / FQ;
    int fq = c - b * FQ;
    const float* hp = hx + (size_t)b * HXS + n * UNITS;
    float v0, v1, v2, v3;
    if (fq == 0) {
      const float* ip = inputs + (size_t)b * INS + n * IND;
      v0 = ip[0]; v1 = ip[1]; v2 = hp[0]; v3 = hp[1];
    } else if (fq < 16) {
      f32x2 a = *reinterpret_cast<const f32x2*>(hp + fq * 4 - 2);
      f32x2 d = *reinterpret_cast<const f32x2*>(hp + fq * 4);
      v0 = a[0]; v1 = a[1]; v2 = d[0]; v3 = d[1];
    } else {
      f32x2 a = *reinterpret_cast<const f32x2*>(hp + 62);
      v0 = a[0]; v1 = a[1]; v2 = 0.f; v3 = 0.f;
    }
    X8[i] = pk4fp8(v0, v1, v2, v3);
    X0bf[i] = make_uint2(cvt2bf(v0, v1), cvt2bf(v2, v3));
  }
}

// ===== paired gather: 2 nodes, all loads issued upfront (16 gathers in flight) =====
__device__ __forceinline__ void gather2(const unsigned* __restrict__ X8t,
                                        int degA, const u64* __restrict__ ebkA,
                                        int degB, const u64* __restrict__ ebkB,
                                        int t,
                                        unsigned owA0, unsigned owA1,
                                        unsigned owA0e, unsigned owA1e,
                                        unsigned owB0, unsigned owB1,
                                        unsigned owB0e, unsigned owB1e,
                                        unsigned short* YA, unsigned short* YB) {
  const bool extra = t < 16;
  const int c = t, c2 = 256 + t;
  if (t < 48) {                       // zero LDS pads fq' 17..19 (both nodes)
    int b = t / 3, fqp = 17 + (t - (t / 3) * 3);
    *reinterpret_cast<uint4*>(YA + (b * LDSC + fqp) * 8) = make_uint4(0u, 0u, 0u, 0u);
    *reinterpret_cast<uint4*>(YB + (b * LDSC + fqp) * 8) = make_uint4(0u, 0u, 0u, 0u);
  }
  const unsigned* bc = X8t + c;
  const unsigned* bc2 = X8t + c2;

  // packet loads for BOTH nodes issue upfront
  u64 pA[8], pB[8];
#pragma unroll
  for (int j = 0; j < 8; ++j) pA[j] = ebkA[j];
#pragma unroll
  for (int j = 0; j < 8; ++j) pB[j] = ebkB[j];
  unsigned oA[8], oB[8]; float vA[8], vB[8];
#pragma unroll
  for (int j = 0; j < 8; ++j) {
    bool on = j < degA;
    oA[j] = on ? (unsigned)pA[j] : 0u;
    vA[j] = on ? __uint_as_float((unsigned)(pA[j] >> 32)) : 0.f;
  }
#pragma unroll
  for (int j = 0; j < 8; ++j) {
    bool on = j < degB;
    oB[j] = on ? (unsigned)pB[j] : 0u;
    vB[j] = on ? __uint_as_float((unsigned)(pB[j] >> 32)) : 0.f;
  }
  // all 16 gathered loads back-to-back
  unsigned wA[8], wB[8];
#pragma unroll
  for (int j = 0; j < 8; ++j) wA[j] = bc[oA[j]];
#pragma unroll
  for (int j = 0; j < 8; ++j) wB[j] = bc[oB[j]];
  unsigned yA[8], yB[8];
  if (extra) {
#pragma unroll
    for (int j = 0; j < 8; ++j) yA[j] = bc2[oA[j]];
#pragma unroll
    for (int j = 0; j < 8; ++j) yB[j] = bc2[oB[j]];
  }

  f32x2 gA01 = {0.f, 0.f}, gA23 = {0.f, 0.f}, geA01 = {0.f, 0.f}, geA23 = {0.f, 0.f};
  f32x2 gB01 = {0.f, 0.f}, gB23 = {0.f, 0.f}, geB01 = {0.f, 0.f}, geB23 = {0.f, 0.f};
#pragma unroll
  for (int j = 0; j < 8; ++j) {
    f32x2 vv = {vA[j], vA[j]};
    gA01 += vv * __builtin_amdgcn_cvt_pk_f32_fp8((int)wA[j], false);
    gA23 += vv * __builtin_amdgcn_cvt_pk_f32_fp8((int)wA[j], true);
    if (extra) {
      geA01 += vv * __builtin_amdgcn_cvt_pk_f32_fp8((int)yA[j], false);
      geA23 += vv * __builtin_amdgcn_cvt_pk_f32_fp8((int)yA[j], true);
    }
  }
#pragma unroll
  for (int j = 0; j < 8; ++j) {
    f32x2 vv = {vB[j], vB[j]};
    gB01 += vv * __builtin_amdgcn_cvt_pk_f32_fp8((int)wB[j], false);
    gB23 += vv * __builtin_amdgcn_cvt_pk_f32_fp8((int)wB[j], true);
    if (extra) {
      geB01 += vv * __builtin_amdgcn_cvt_pk_f32_fp8((int)yB[j], false);
      geB23 += vv * __builtin_amdgcn_cvt_pk_f32_fp8((int)yB[j], true);
    }
  }
  // tails (deg > 8, rare): masked 4-wide per node
  for (int e = 8; e < degA; e += 4) {
    unsigned o[4]; float v[4];
#pragma unroll
    for (int j = 0; j < 4; ++j) {
      int ee = e + j;
      u64 p = ebkA[ee < CAP ? ee : CAP - 1];
      bool on = ee < degA;
      o[j] = on ? (unsigned)p : 0u;
      v[j] = on ? __uint_as_float((unsigned)(p >> 32)) : 0.f;
    }
    unsigned wv[4];
#pragma unroll
    for (int j = 0; j < 4; ++j) wv[j] = bc[o[j]];
    unsigned yv[4];
    if (extra) {
#pragma unroll
      for (int j = 0; j < 4; ++j) yv[j] = bc2[o[j]];
    }
#pragma unroll
    for (int j = 0; j < 4; ++j) {
      f32x2 vv = {v[j], v[j]};
      gA01 += vv * __builtin_amdgcn_cvt_pk_f32_fp8((int)wv[j], false);
      gA23 += vv * __builtin_amdgcn_cvt_pk_f32_fp8((int)wv[j], true);
      if (extra) {
        geA01 += vv * __builtin_amdgcn_cvt_pk_f32_fp8((int)yv[j], false);
        geA23 += vv * __builtin_amdgcn_cvt_pk_f32_fp8((int)yv[j], true);
      }
    }
  }
  for (int e = 8; e < degB; e += 4) {
    unsigned o[4]; float v[4];
#pragma unroll
    for (int j = 0; j < 4; ++j) {
      int ee = e + j;
      u64 p = ebkB[ee < CAP ? ee : CAP - 1];
      bool on = ee < degB;
      o[j] = on ? (unsigned)p : 0u;
      v[j] = on ? __uint_as_float((unsigned)(p >> 32)) : 0.f;
    }
    unsigned wv[4];
#pragma unroll
    for (int j = 0; j < 4; ++j) wv[j] = bc[o[j]];
    unsigned yv[4];
    if (extra) {
#pragma unroll
      for (int j = 0; j < 4; ++j) yv[j] = bc2[o[j]];
    }
#pragma unroll
    for (int j = 0; j < 4; ++j) {
      f32x2 vv = {v[j], v[j]};
      gB01 += vv * __builtin_amdgcn_cvt_pk_f32_fp8((int)wv[j], false);
      gB23 += vv * __builtin_amdgcn_cvt_pk_f32_fp8((int)wv[j], true);
      if (extra) {
        geB01 += vv * __builtin_amdgcn_cvt_pk_f32_fp8((int)yv[j], false);
        geB23 += vv * __builtin_amdgcn_cvt_pk_f32_fp8((int)yv[j], true);
      }
    }
  }

  int b = c / FQ, fq = c - (c / FQ) * FQ;
  *reinterpret_cast<uint4*>(YA + (b * LDSC + fq) * 8) =
      make_uint4(owA0, owA1, cvt2bf(gA01[0], gA01[1]), cvt2bf(gA23[0], gA23[1]));
  *reinterpret_cast<uint4*>(YB + (b * LDSC + fq) * 8) =
      make_uint4(owB0, owB1, cvt2bf(gB01[0], gB01[1]), cvt2bf(gB23[0], gB23[1]));
  if (extra) {
    *reinterpret_cast<uint4*>(YA + (15 * LDSC + (t + 1)) * 8) =
        make_uint4(owA0e, owA1e, cvt2bf(geA01[0], geA01[1]), cvt2bf(geA23[0], geA23[1]));
    *reinterpret_cast<uint4*>(YB + (15 * LDSC + (t + 1)) * 8) =
        make_uint4(owB0e, owB1e, cvt2bf(geB01[0], geB01[1]), cvt2bf(geB23[0], geB23[1]));
  }
}

// A-frag: lane (ml,s) kt reads 16B = (x0[f0..f0+3], x1[f0..f0+3]), f0 = kt*16+s*4
__device__ __forceinline__ void build_afrag(const unsigned short* Y, int ml, int s, bf16x8* af) {
#pragma unroll
  for (int kt = 0; kt < KTILES; ++kt)
    af[kt] = *reinterpret_cast<const bf16x8*>(Y + (ml * LDSC + kt * 4 + s) * 8);
}

// ------- gates: 2 nodes/block; gconv1 (MFMA) + sigmoid;
//         r*h -> X8c (fp8, LDS-staged), {u,u*h} -> upk. -------
__global__ __launch_bounds__(256) void gates_kernel(
    const uint2* __restrict__ X0bf, const unsigned* __restrict__ X8,
    const short* __restrict__ W1p, const float* __restrict__ B1,
    const int* __restrict__ cnt, const u64* __restrict__ epk,
    unsigned* __restrict__ X8c, unsigned* __restrict__ upk) {
  __shared__ __align__(16) unsigned short Y[2][16 * LDSC * 8];
  __shared__ __align__(16) unsigned X8s[2][CHUNKS];
  int t = threadIdx.x;
  int lane = t & 63, w = t >> 6;
  int nA = 2 * blockIdx.x, nB = nA + 1;

  const uint2* xrA = X0bf + (size_t)nA * CHUNKS;
  const uint2* xrB = X0bf + (size_t)nB * CHUNKS;
  uint2 ownA = xrA[t], ownB = xrB[t];
  int b0 = t / FQ, fq0 = t - b0 * FQ;
  X8s[0][t] = (fq0 == 0)
      ? pk4fp8(bf2f((unsigned short)(ownA.x & 0xffffu)), bf2f((unsigned short)(ownA.x >> 16)), 0.f, 0.f)
      : 0u;
  X8s[1][t] = (fq0 == 0)
      ? pk4fp8(bf2f((unsigned short)(ownB.x & 0xffffu)), bf2f((unsigned short)(ownB.x >> 16)), 0.f, 0.f)
      : 0u;
  unsigned owA0e = 0, owA1e = 0, owB0e = 0, owB1e = 0;
  if (t < 16) {
    uint2 a2 = xrA[256 + t], b2 = xrB[256 + t];
    owA0e = a2.x; owA1e = a2.y; owB0e = b2.x; owB1e = b2.y;
    X8s[0][256 + t] = 0u; X8s[1][256 + t] = 0u;
  }

  int degA = cnt[nA]; if (degA > CAP) degA = CAP;
  int degB = cnt[nB]; if (degB > CAP) degB = CAP;
  gather2(X8, degA, epk + (size_t)nA * CAP, degB, epk + (size_t)nB * CAP, t,
          ownA.x, ownA.y, owA0e, owA1e, ownB.x, ownB.y, owB0e, owB1e, Y[0], Y[1]);
  __syncthreads();

  int ml = lane & 15, s = lane >> 4;
  const bf16x8* Wp = (const bf16x8*)W1p;
#pragma unroll
  for (int nn = 0; nn < 2; ++nn) {
    int n = nA + nn;
    const unsigned short* Yn = Y[nn];
    bf16x8 af[KTILES];
    build_afrag(Yn, ml, s, af);
#pragma unroll
    for (int q = 0; q < 2; ++q) {
      int nt = w * 2 + q;
      f32x4 acc = {0.f, 0.f, 0.f, 0.f};
#pragma unroll
      for (int kt = 0; kt < KTILES; ++kt)
        acc = __builtin_amdgcn_mfma_f32_16x16x32_bf16(af[kt], Wp[(nt * KTILES + kt) * 64 + lane],
                                                      acc, 0, 0, 0);
      int o = nt * 16 + ml;           // output col; rows = batch s*4+r
      float bias = B1[o];
      int f = (o < UNITS ? o : o - UNITS) + IND, fqi = f >> 2, fr = f & 3;
      if (o < UNITS) {
#pragma unroll
        for (int r = 0; r < 4; ++r) {
          int b = s * 4 + r;
          float h = bf2f(Yn[(b * LDSC + fqi) * 8 + fr]);   // h (bf16) from staged own-row x0
          float sg = 1.f / (1.f + __expf(-(acc[r] + bias)));
          ((unsigned char*)X8s[nn])[(b * FQ + fqi) * 4 + fr] = f2fp8(sg * h);
        }
      } else {
        int ou = o - UNITS;
#pragma unroll
        for (int r = 0; r < 4; ++r) {
          int b = s * 4 + r;
          float h = bf2f(Yn[(b * LDSC + fqi) * 8 + fr]);
          float u = 1.f / (1.f + __expf(-(acc[r] + bias)));
          upk[(size_t)b * HXS + n * UNITS + ou] = cvt2bf(u, u * h);
        }
      }
    }
  }
  __syncthreads();                   // X8s bytes complete
#pragma unroll
  for (int nn = 0; nn < 2; ++nn) {
    int n = nA + nn;
    X8c[(size_t)n * CHUNKS + t] = X8s[nn][t];
    if (t < 16) X8c[(size_t)n * CHUNKS + 256 + t] = X8s[nn][256 + t];
  }
}

// ------- candidate: 2 nodes/block; gconv2 (MFMA) + tanh + GRU combine -------
__global__ __launch_bounds__(256) void cand_kernel(
    const unsigned* __restrict__ X8c, const short* __restrict__ W2p,
    const float* __restrict__ B2,
    const int* __restrict__ cnt, const u64* __restrict__ epk,
    const unsigned* __restrict__ upk, float* __restrict__ out) {
  __shared__ __align__(16) unsigned short Y[2][16 * LDSC * 8];
  int t = threadIdx.x;
  int lane = t & 63, w = t >> 6;
  int nA = 2 * blockIdx.x, nB = nA + 1;

  const unsigned* xrA = X8c + (size_t)nA * CHUNKS;
  const unsigned* xrB = X8c + (size_t)nB * CHUNKS;
  unsigned woA = xrA[t], woB = xrB[t];
  f32x2 loA = __builtin_amdgcn_cvt_pk_f32_fp8((int)woA, false);
  f32x2 hiA = __builtin_amdgcn_cvt_pk_f32_fp8((int)woA, true);
  f32x2 loB = __builtin_amdgcn_cvt_pk_f32_fp8((int)woB, false);
  f32x2 hiB = __builtin_amdgcn_cvt_pk_f32_fp8((int)woB, true);
  unsigned owA0 = cvt2bf(loA[0], loA[1]), owA1 = cvt2bf(hiA[0], hiA[1]);
  unsigned owB0 = cvt2bf(loB[0], loB[1]), owB1 = cvt2bf(hiB[0], hiB[1]);
  unsigned owA0e = 0, owA1e = 0, owB0e = 0, owB1e = 0;
  if (t < 16) {
    unsigned wa2 = xrA[256 + t], wb2 = xrB[256 + t];
    f32x2 la = __builtin_amdgcn_cvt_pk_f32_fp8((int)wa2, false);
    f32x2 ha = __builtin_amdgcn_cvt_pk_f32_fp8((int)wa2, true);
    f32x2 lb = __builtin_amdgcn_cvt_pk_f32_fp8((int)wb2, false);
    f32x2 hb = __builtin_amdgcn_cvt_pk_f32_fp8((int)wb2, true);
    owA0e = cvt2bf(la[0], la[1]); owA1e = cvt2bf(ha[0], ha[1]);
    owB0e = cvt2bf(lb[0], lb[1]); owB1e = cvt2bf(hb[0], hb[1]);
  }

  int degA = cnt[nA]; if (degA > CAP) degA = CAP;
  int degB = cnt[nB]; if (degB > CAP) degB = CAP;
  gather2(X8c, degA, epk + (size_t)nA * CAP, degB, epk + (size_t)nB * CAP, t,
          owA0, owA1, owA0e, owA1e, owB0, owB1, owB0e, owB1e, Y[0], Y[1]);
  __syncthreads();

  int ml = lane & 15, s = lane >> 4;
  const bf16x8* Wp = (const bf16x8*)W2p;
#pragma unroll
  for (int nn = 0; nn < 2; ++nn) {
    int n = nA + nn;
    bf16x8 af[KTILES];
    build_afrag(Y[nn], ml, s, af);
    f32x4 acc = {0.f, 0.f, 0.f, 0.f};
#pragma unroll
    for (int kt = 0; kt < KTILES; ++kt)
      acc = __builtin_amdgcn_mfma_f32_16x16x32_bf16(af[kt], Wp[(w * KTILES + kt) * 64 + lane],
                                                    acc, 0, 0, 0);
    int o = w * 16 + ml;
    float bias = B2[o];
#pragma unroll
    for (int r = 0; r < 4; ++r) {
      int b = s * 4 + r;
      size_t idx = (size_t)b * HXS + n * UNITS + o;
      float x = acc[r] + bias;
      float c = 1.f - 2.f / (__expf(2.f * x) + 1.f);   // tanh
      unsigned pk = upk[idx];
      float u = bf2f((unsigned short)(pk & 0xffffu));
      float uh = bf2f((unsigned short)(pk >> 16));
      out[idx] = uh + (1.f - u) * c;
    }
  }
}

extern "C" void kernel_launch(void* const* d_in, const int* in_sizes, int n_in,
                              void* d_out, int out_size, void* d_ws, size_t ws_size,
                              hipStream_t stream) {
  const float* inputs = (const float*)d_in[0];
  const float* hx     = (const float*)d_in[1];
  const float* eval   = (const float*)d_in[2];
  const float* w1mu   = (const float*)d_in[3];
  const float* w1ls   = (const float*)d_in[4];
  const float* b1mu   = (const float*)d_in[5];
  const float* b1ls   = (const float*)d_in[6];
  const float* w2mu   = (const float*)d_in[7];
  const float* w2ls   = (const float*)d_in[8];
  const float* b2mu   = (const float*)d_in[9];
  const float* b2ls   = (const float*)d_in[10];
  const float* ew1    = (const float*)d_in[11];
  const float* eb1    = (const float*)d_in[12];
  const float* ew2    = (const float*)d_in[13];
  const float* eb2    = (const float*)d_in[14];
  const int* erow     = (const int*)d_in[15];
  const int* ecol     = (const int*)d_in[16];
  float* out = (float*)d_out;

  char* p = (char*)d_ws;
  short* W1p = (short*)p;                   p += 20480 * 2;
  short* W2p = (short*)p;                   p += 10240 * 2;
  float* B1  = (float*)p;                   p += 128 * 4;
  float* B2  = (float*)p;                   p += 64 * 4;
  unsigned* X8  = (unsigned*)p;             p += (size_t)N_NODES * CHUNKS * 4;
  unsigned* X8c = (unsigned*)p;             p += (size_t)N_NODES * CHUNKS * 4;
  uint2* X0bf = (uint2*)p;                  p += (size_t)N_NODES * CHUNKS * 8;
  unsigned* upk = (unsigned*)p;             p += (size_t)BATCH * HXS * 4;
  int* cnt    = (int*)p;                    p += N_NODES * 4;
  u64* epk    = (u64*)p;                    p += (size_t)N_NODES * CAP * 8;

  hipMemsetAsync(cnt, 0, N_NODES * sizeof(int), stream);
  prep_kernel<<<16 + 313 + (N_NODES * CHUNKS) / 256, 256, 0, stream>>>(
      inputs, hx, w1mu, w1ls, ew1, b1mu, b1ls, eb1,
      w2mu, w2ls, ew2, b2mu, b2ls, eb2, erow, ecol, eval,
      W1p, W2p, B1, B2, cnt, epk, X8, X0bf);
  gates_kernel<<<N_NODES / 2, 256, 0, stream>>>(X0bf, X8, W1p, B1, cnt, epk, X8c, upk);
  cand_kernel<<<N_NODES / 2, 256, 0, stream>>>(X8c, W2p, B2, cnt, epk, upk, out);
}

// Round 15
// 90.612 us; speedup vs baseline: 1.0300x; 1.0300x over previous
//
#include <hip/hip_runtime.h>
#include <cmath>

#define N_NODES 10000
#define UNITS   64
#define IND     2
#define BATCH   16
#define NEDGE   80000
#define FDIM    66            // IND + UNITS
#define OG      128           // 2*UNITS
#define OC      64            // UNITS
#define HXS     (N_NODES*UNITS)
#define INS     (N_NODES*IND)
#define KTILES  5             // ceil(132/32)
#define FQ      17            // f-quads per row (F padded 66->68)
#define CHUNKS  272           // 16*17 quads per row
#define LDSC    21            // padded fq stride in LDS
#define CAP     64            // bucket capacity per node (mean deg 8)

typedef __attribute__((ext_vector_type(8))) short bf16x8;
typedef __attribute__((ext_vector_type(4))) float f32x4;
typedef __attribute__((ext_vector_type(2))) float f32x2;
typedef unsigned long long u64;

__device__ __forceinline__ float bf2f(unsigned short u) {
  union { unsigned u; float f; } v; v.u = ((unsigned)u) << 16; return v.f;
}
__device__ __forceinline__ unsigned short f2bf(float x) {
  union { float f; unsigned u; } v; v.f = x;
  unsigned r = v.u + 0x7fffu + ((v.u >> 16) & 1u);
  return (unsigned short)(r >> 16);
}
__device__ __forceinline__ unsigned cvt2bf(float a, float b) {   // lo=bf16(a), hi=bf16(b)
  unsigned r; asm("v_cvt_pk_bf16_f32 %0, %1, %2" : "=v"(r) : "v"(a), "v"(b)); return r;
}
__device__ __forceinline__ unsigned pk4fp8(float a, float b, float c, float d) {
  int v = __builtin_amdgcn_cvt_pk_fp8_f32(a, b, 0, false);
  v = __builtin_amdgcn_cvt_pk_fp8_f32(c, d, v, true);
  return (unsigned)v;
}
__device__ __forceinline__ unsigned char f2fp8(float a) {
  return (unsigned char)(__builtin_amdgcn_cvt_pk_fp8_f32(a, 0.f, 0, false) & 0xff);
}

// ================= fused prep: pack W | fill buckets | build X8 + X0bf =================
// k-order for A/B frags: k = kt*32 + s*8 + j -> feature f = kt*16 + s*4 + (j&3),
// src = j>>2 (0=x0, 1=x1) -> original W row = 2*f + src.
__global__ __launch_bounds__(256) void prep_kernel(
    const float* __restrict__ inputs, const float* __restrict__ hx,
    const float* __restrict__ w1mu, const float* __restrict__ w1ls, const float* __restrict__ ew1,
    const float* __restrict__ b1mu, const float* __restrict__ b1ls, const float* __restrict__ eb1,
    const float* __restrict__ w2mu, const float* __restrict__ w2ls, const float* __restrict__ ew2,
    const float* __restrict__ b2mu, const float* __restrict__ b2ls, const float* __restrict__ eb2,
    const int* __restrict__ erow, const int* __restrict__ ecol, const float* __restrict__ eval,
    short* __restrict__ W1p, short* __restrict__ W2p,
    float* __restrict__ B1, float* __restrict__ B2,
    int* __restrict__ cnt, u64* __restrict__ epk,
    unsigned* __restrict__ X8, uint2* __restrict__ X0bf) {
  int blk = blockIdx.x, t = threadIdx.x;
  if (blk < 16) {                    // ---- pack W (fused reparam) ----
    int i = blk * 256 + t;
    if (i < 2560) {
      int l = i & 63, kt = (i >> 6) % KTILES, nt = i / (KTILES * 64);
      int o = nt * 16 + (l & 15), s = l >> 4;
      bf16x8 fr;
#pragma unroll
      for (int j = 0; j < 8; ++j) {
        int f = kt * 16 + s * 4 + (j & 3);
        int src = j >> 2;
        float w = 0.f;
        if (f < FDIM) { int idx = (2 * f + src) * OG + o; w = w1mu[idx] + __expf(w1ls[idx]) * ew1[idx]; }
        fr[j] = (short)f2bf(w);
      }
      *((bf16x8*)W1p + i) = fr;
    } else if (i < 3840) {
      int i2 = i - 2560;
      int l = i2 & 63, kt = (i2 >> 6) % KTILES, nt = i2 / (KTILES * 64);
      int o = nt * 16 + (l & 15), s = l >> 4;
      bf16x8 fr;
#pragma unroll
      for (int j = 0; j < 8; ++j) {
        int f = kt * 16 + s * 4 + (j & 3);
        int src = j >> 2;
        float w = 0.f;
        if (f < FDIM) { int idx = (2 * f + src) * OC + o; w = w2mu[idx] + __expf(w2ls[idx]) * ew2[idx]; }
        fr[j] = (short)f2bf(w);
      }
      *((bf16x8*)W2p + i2) = fr;
    } else if (i < 3968) {
      int j = i - 3840; B1[j] = b1mu[j] + __expf(b1ls[j]) * eb1[j];
    } else if (i < 4032) {
      int j = i - 3968; B2[j] = b2mu[j] + __expf(b2ls[j]) * eb2[j];
    }
  } else if (blk < 16 + 313) {       // ---- fill buckets ----
    int i = (blk - 16) * 256 + t;
    if (i < NEDGE) {
      int r = erow[i];
      int pos = atomicAdd(&cnt[r], 1);
      if (pos < CAP)
        epk[(size_t)r * CAP + pos] =
            (u64)(unsigned)(ecol[i] * CHUNKS) | ((u64)__float_as_uint(eval[i]) << 32);
    }
  } else {                           // ---- build X8 (fp8) + X0bf (bf16) ----
    int i = (blk - 329) * 256 + t;
    if (i >= N_NODES * CHUNKS) return;
    int n = i / CHUNKS;
    int c = i - n * CHUNKS;
    int b = c / FQ;
    int fq = c - b * FQ;
    const float* hp = hx + (size_t)b * HXS + n * UNITS;
    float v0, v1, v2, v3;
    if (fq == 0) {
      const float* ip = inputs + (size_t)b * INS + n * IND;
      v0 = ip[0]; v1 = ip[1]; v2 = hp[0]; v3 = hp[1];
    } else if (fq < 16) {
      f32x2 a = *reinterpret_cast<const f32x2*>(hp + fq * 4 - 2);
      f32x2 d = *reinterpret_cast<const f32x2*>(hp + fq * 4);
      v0 = a[0]; v1 = a[1]; v2 = d[0]; v3 = d[1];
    } else {
      f32x2 a = *reinterpret_cast<const f32x2*>(hp + 62);
      v0 = a[0]; v1 = a[1]; v2 = 0.f; v3 = 0.f;
    }
    X8[i] = pk4fp8(v0, v1, v2, v3);
    X0bf[i] = make_uint2(cvt2bf(v0, v1), cvt2bf(v2, v3));
  }
}

// ===== gather: fp8 x1 gather + Y write. Straight-line masked 8-edge head =====
// (buckets are CAP-sized and always readable; masked edges contribute exact 0.0)
__device__ __forceinline__ void gather_write(const unsigned* __restrict__ X8t,
                                             int deg, const u64* __restrict__ ebk,
                                             int t, unsigned ow0, unsigned ow1,
                                             unsigned ow0e, unsigned ow1e,
                                             unsigned short* Y) {
  const bool extra = t < 16;
  const int c = t, c2 = 256 + t;
  if (t < 48) {                       // zero LDS pads fq' 17..19
    int b = t / 3, fqp = 17 + (t - (t / 3) * 3);
    *reinterpret_cast<uint4*>(Y + (b * LDSC + fqp) * 8) = make_uint4(0u, 0u, 0u, 0u);
  }
  f32x2 g01 = {0.f, 0.f}, g23 = {0.f, 0.f}, ge01 = {0.f, 0.f}, ge23 = {0.f, 0.f};
  const unsigned* bc = X8t + c;
  const unsigned* bc2 = X8t + c2;

  // ---- head: 8 edges, fully unrolled, masked ----
  {
    unsigned o[8]; float v[8];
#pragma unroll
    for (int j = 0; j < 8; ++j) {
      u64 p = ebk[j];                      // all packet loads issue upfront
      bool on = j < deg;
      o[j] = on ? (unsigned)p : 0u;
      v[j] = on ? __uint_as_float((unsigned)(p >> 32)) : 0.f;
    }
    unsigned wv[8];
#pragma unroll
    for (int j = 0; j < 8; ++j) wv[j] = bc[o[j]];   // gathered loads back-to-back
    unsigned yv[8];
    if (extra) {
#pragma unroll
      for (int j = 0; j < 8; ++j) yv[j] = bc2[o[j]];
    }
#pragma unroll
    for (int j = 0; j < 8; ++j) {
      f32x2 vv = {v[j], v[j]};
      g01 += vv * __builtin_amdgcn_cvt_pk_f32_fp8((int)wv[j], false);
      g23 += vv * __builtin_amdgcn_cvt_pk_f32_fp8((int)wv[j], true);
      if (extra) {
        ge01 += vv * __builtin_amdgcn_cvt_pk_f32_fp8((int)yv[j], false);
        ge23 += vv * __builtin_amdgcn_cvt_pk_f32_fp8((int)yv[j], true);
      }
    }
  }
  // ---- tail: deg > 8, masked 4-wide blocks ----
  for (int e = 8; e < deg; e += 4) {
    unsigned o[4]; float v[4];
#pragma unroll
    for (int j = 0; j < 4; ++j) {
      int ee = e + j;
      u64 p = ebk[ee < CAP ? ee : CAP - 1];
      bool on = ee < deg;
      o[j] = on ? (unsigned)p : 0u;
      v[j] = on ? __uint_as_float((unsigned)(p >> 32)) : 0.f;
    }
    unsigned wv[4];
#pragma unroll
    for (int j = 0; j < 4; ++j) wv[j] = bc[o[j]];
    unsigned yv[4];
    if (extra) {
#pragma unroll
      for (int j = 0; j < 4; ++j) yv[j] = bc2[o[j]];
    }
#pragma unroll
    for (int j = 0; j < 4; ++j) {
      f32x2 vv = {v[j], v[j]};
      g01 += vv * __builtin_amdgcn_cvt_pk_f32_fp8((int)wv[j], false);
      g23 += vv * __builtin_amdgcn_cvt_pk_f32_fp8((int)wv[j], true);
      if (extra) {
        ge01 += vv * __builtin_amdgcn_cvt_pk_f32_fp8((int)yv[j], false);
        ge23 += vv * __builtin_amdgcn_cvt_pk_f32_fp8((int)yv[j], true);
      }
    }
  }

  int b = c / FQ, fq = c - (c / FQ) * FQ;
  *reinterpret_cast<uint4*>(Y + (b * LDSC + fq) * 8) =
      make_uint4(ow0, ow1, cvt2bf(g01[0], g01[1]), cvt2bf(g23[0], g23[1]));
  if (extra) {
    *reinterpret_cast<uint4*>(Y + (15 * LDSC + (t + 1)) * 8) =
        make_uint4(ow0e, ow1e, cvt2bf(ge01[0], ge01[1]), cvt2bf(ge23[0], ge23[1]));
  }
}

// A-frag: lane (ml,s) kt reads 16B = (x0[f0..f0+3], x1[f0..f0+3]), f0 = kt*16+s*4
__device__ __forceinline__ void build_afrag(const unsigned short* Y, int ml, int s, bf16x8* af) {
#pragma unroll
  for (int kt = 0; kt < KTILES; ++kt)
    af[kt] = *reinterpret_cast<const bf16x8*>(Y + (ml * LDSC + kt * 4 + s) * 8);
}

// ------- gates: own row from X0bf (bf16); gconv1 (MFMA) + sigmoid;
//         r*h -> X8c (fp8, LDS-staged), {u,u*h} -> upk.  2 barriers total. -------
__global__ __launch_bounds__(256, 8) void gates_kernel(
    const uint2* __restrict__ X0bf, const unsigned* __restrict__ X8,
    const short* __restrict__ W1p, const float* __restrict__ B1,
    const int* __restrict__ cnt, const u64* __restrict__ epk,
    unsigned* __restrict__ X8c, unsigned* __restrict__ upk) {
  __shared__ __align__(16) unsigned short Y[16 * LDSC * 8];
  __shared__ __align__(16) unsigned X8s[CHUNKS];
  int n = blockIdx.x, t = threadIdx.x;
  int lane = t & 63, w = t >> 6;

  // own row: one coalesced 8B bf16 load
  const uint2* xrow = X0bf + (size_t)n * CHUNKS;
  uint2 own = xrow[t];
  unsigned ow0 = own.x, ow1 = own.y;
  int b0 = t / FQ, fq0 = t - b0 * FQ;
  X8s[t] = (fq0 == 0)
      ? pk4fp8(bf2f((unsigned short)(ow0 & 0xffffu)), bf2f((unsigned short)(ow0 >> 16)), 0.f, 0.f)
      : 0u;
  unsigned ow0e = 0, ow1e = 0;
  if (t < 16) {
    uint2 own2 = xrow[256 + t];
    ow0e = own2.x; ow1e = own2.y;
    X8s[256 + t] = 0u;               // fq = t+1 != 0
  }

  int deg = cnt[n]; if (deg > CAP) deg = CAP;
  gather_write(X8, deg, epk + (size_t)n * CAP, t, ow0, ow1, ow0e, ow1e, Y);
  __syncthreads();                   // Y + X8s init complete

  int ml = lane & 15, s = lane >> 4;
  bf16x8 af[KTILES];
  build_afrag(Y, ml, s, af);

  const bf16x8* Wp = (const bf16x8*)W1p;
#pragma unroll
  for (int q = 0; q < 2; ++q) {
    int nt = w * 2 + q;
    f32x4 acc = {0.f, 0.f, 0.f, 0.f};
#pragma unroll
    for (int kt = 0; kt < KTILES; ++kt)
      acc = __builtin_amdgcn_mfma_f32_16x16x32_bf16(af[kt], Wp[(nt * KTILES + kt) * 64 + lane],
                                                    acc, 0, 0, 0);
    int o = nt * 16 + ml;           // output col; rows = batch s*4+r
    float bias = B1[o];
    int f = (o < UNITS ? o : o - UNITS) + IND, fqi = f >> 2, fr = f & 3;
    if (o < UNITS) {
#pragma unroll
      for (int r = 0; r < 4; ++r) {
        int b = s * 4 + r;
        float h = bf2f(Y[(b * LDSC + fqi) * 8 + fr]);   // h (bf16) from staged own-row x0 quad
        float sg = 1.f / (1.f + __expf(-(acc[r] + bias)));
        ((unsigned char*)X8s)[(b * FQ + fqi) * 4 + fr] = f2fp8(sg * h);
      }
    } else {
      int ou = o - UNITS;
#pragma unroll
      for (int r = 0; r < 4; ++r) {
        int b = s * 4 + r;
        float h = bf2f(Y[(b * LDSC + fqi) * 8 + fr]);
        float u = 1.f / (1.f + __expf(-(acc[r] + bias)));
        upk[(size_t)b * HXS + n * UNITS + ou] = cvt2bf(u, u * h);
      }
    }
  }
  __syncthreads();                   // X8s bytes complete
  // coalesced fp8 row store
  X8c[(size_t)n * CHUNKS + t] = X8s[t];
  if (t < 16) X8c[(size_t)n * CHUNKS + 256 + t] = X8s[256 + t];
}

// ------- candidate: gconv2 (MFMA) + tanh + GRU combine. 1 barrier total. -------
__global__ __launch_bounds__(256, 8) void cand_kernel(
    const unsigned* __restrict__ X8c, const short* __restrict__ W2p,
    const float* __restrict__ B2,
    const int* __restrict__ cnt, const u64* __restrict__ epk,
    const unsigned* __restrict__ upk, float* __restrict__ out) {
  __shared__ __align__(16) unsigned short Y[16 * LDSC * 8];
  int n = blockIdx.x, t = threadIdx.x;
  int lane = t & 63, w = t >> 6;

  // own row from fp8 table
  const unsigned* xrow = X8c + (size_t)n * CHUNKS;
  unsigned wo = xrow[t];
  f32x2 lo = __builtin_amdgcn_cvt_pk_f32_fp8((int)wo, false);
  f32x2 hi = __builtin_amdgcn_cvt_pk_f32_fp8((int)wo, true);
  unsigned ow0 = cvt2bf(lo[0], lo[1]), ow1 = cvt2bf(hi[0], hi[1]);
  unsigned ow0e = 0, ow1e = 0;
  if (t < 16) {
    unsigned wo2 = xrow[256 + t];
    f32x2 lo2 = __builtin_amdgcn_cvt_pk_f32_fp8((int)wo2, false);
    f32x2 hi2 = __builtin_amdgcn_cvt_pk_f32_fp8((int)wo2, true);
    ow0e = cvt2bf(lo2[0], lo2[1]); ow1e = cvt2bf(hi2[0], hi2[1]);
  }

  int deg = cnt[n]; if (deg > CAP) deg = CAP;
  gather_write(X8c, deg, epk + (size_t)n * CAP, t, ow0, ow1, ow0e, ow1e, Y);
  __syncthreads();

  int ml = lane & 15, s = lane >> 4;
  bf16x8 af[KTILES];
  build_afrag(Y, ml, s, af);

  const bf16x8* Wp = (const bf16x8*)W2p;
  f32x4 acc = {0.f, 0.f, 0.f, 0.f};
#pragma unroll
  for (int kt = 0; kt < KTILES; ++kt)
    acc = __builtin_amdgcn_mfma_f32_16x16x32_bf16(af[kt], Wp[(w * KTILES + kt) * 64 + lane],
                                                  acc, 0, 0, 0);
  int o = w * 16 + ml;
  float bias = B2[o];
#pragma unroll
  for (int r = 0; r < 4; ++r) {
    int b = s * 4 + r;
    size_t idx = (size_t)b * HXS + n * UNITS + o;
    float x = acc[r] + bias;
    float c = 1.f - 2.f / (__expf(2.f * x) + 1.f);   // tanh
    unsigned pk = upk[idx];
    float u = bf2f((unsigned short)(pk & 0xffffu));
    float uh = bf2f((unsigned short)(pk >> 16));
    out[idx] = uh + (1.f - u) * c;
  }
}

extern "C" void kernel_launch(void* const* d_in, const int* in_sizes, int n_in,
                              void* d_out, int out_size, void* d_ws, size_t ws_size,
                              hipStream_t stream) {
  const float* inputs = (const float*)d_in[0];
  const float* hx     = (const float*)d_in[1];
  const float* eval   = (const float*)d_in[2];
  const float* w1mu   = (const float*)d_in[3];
  const float* w1ls   = (const float*)d_in[4];
  const float* b1mu   = (const float*)d_in[5];
  const float* b1ls   = (const float*)d_in[6];
  const float* w2mu   = (const float*)d_in[7];
  const float* w2ls   = (const float*)d_in[8];
  const float* b2mu   = (const float*)d_in[9];
  const float* b2ls   = (const float*)d_in[10];
  const float* ew1    = (const float*)d_in[11];
  const float* eb1    = (const float*)d_in[12];
  const float* ew2    = (const float*)d_in[13];
  const float* eb2    = (const float*)d_in[14];
  const int* erow     = (const int*)d_in[15];
  const int* ecol     = (const int*)d_in[16];
  float* out = (float*)d_out;

  char* p = (char*)d_ws;
  short* W1p = (short*)p;                   p += 20480 * 2;
  short* W2p = (short*)p;                   p += 10240 * 2;
  float* B1  = (float*)p;                   p += 128 * 4;
  float* B2  = (float*)p;                   p += 64 * 4;
  unsigned* X8  = (unsigned*)p;             p += (size_t)N_NODES * CHUNKS * 4;
  unsigned* X8c = (unsigned*)p;             p += (size_t)N_NODES * CHUNKS * 4;
  uint2* X0bf = (uint2*)p;                  p += (size_t)N_NODES * CHUNKS * 8;
  unsigned* upk = (unsigned*)p;             p += (size_t)BATCH * HXS * 4;
  int* cnt    = (int*)p;                    p += N_NODES * 4;
  u64* epk    = (u64*)p;                    p += (size_t)N_NODES * CAP * 8;

  hipMemsetAsync(cnt, 0, N_NODES * sizeof(int), stream);
  prep_kernel<<<16 + 313 + (N_NODES * CHUNKS) / 256, 256, 0, stream>>>(
      inputs, hx, w1mu, w1ls, ew1, b1mu, b1ls, eb1,
      w2mu, w2ls, ew2, b2mu, b2ls, eb2, erow, ecol, eval,
      W1p, W2p, B1, B2, cnt, epk, X8, X0bf);
  gates_kernel<<<N_NODES, 256, 0, stream>>>(X0bf, X8, W1p, B1, cnt, epk, X8c, upk);
  cand_kernel<<<N_NODES, 256, 0, stream>>>(X8c, W2p, B2, cnt, epk, upk, out);
}